// Round 1
// baseline (158.379 us; speedup 1.0000x reference)
//
#include <hip/hip_runtime.h>

// Problem constants (from reference):
constexpr int kB    = 32;
constexpr int kTin  = 512;
constexpr int kTout = 2048;
constexpr int kA    = 384;   // ADIM
constexpr int kC4   = kA / 4; // 96 float4 per row

// ---------------------------------------------------------------------------
// Kernel A: length regulation index computation.
// One block per batch, 512 threads (= T_IN). Computes masked-duration cumsum
// in LDS (Hillis-Steele scan), then searchsorted(cum, t, 'right') per output
// frame. Writes idx[b, t_out] (source phone index, or -1 for padded frames).
// ---------------------------------------------------------------------------
__global__ __launch_bounds__(kTin) void lr_index_kernel(
    const int* __restrict__ durations,      // [B, T_IN]
    const int* __restrict__ input_lengths,  // [B]
    int* __restrict__ idx_out)              // [B, T_OUT]
{
    __shared__ int cum[kTin];
    const int b = blockIdx.x;
    const int t = threadIdx.x;
    const int len = input_lengths[b];
    const bool valid = t < len;
    int dval = valid ? durations[b * kTin + t] : 0;
    int total = 0;
    // Up to 2 passes: reference refills d with ones (at valid positions) if
    // the masked sum is zero. Branch on `total` is block-uniform.
    for (int pass = 0; pass < 2; ++pass) {
        __syncthreads();
        cum[t] = dval;
        __syncthreads();
        for (int off = 1; off < kTin; off <<= 1) {
            int add = (t >= off) ? cum[t - off] : 0;
            __syncthreads();
            cum[t] += add;
            __syncthreads();
        }
        total = cum[kTin - 1];
        if (total != 0) break;
        dval = valid ? 1 : 0;
    }
    // Each thread resolves 4 output frames (512 * 4 = 2048), coalesced.
    for (int k = 0; k < kTout / kTin; ++k) {
        const int to = t + k * kTin;
        // first index where cum[i] > to  == count of entries <= to
        int lo = 0, hi = kTin;
        while (lo < hi) {
            const int mid = (lo + hi) >> 1;
            if (cum[mid] <= to) lo = mid + 1; else hi = mid;
        }
        int idx = (lo < kTin) ? lo : (kTin - 1);
        idx_out[b * kTout + to] = (to < total) ? idx : -1;
    }
}

// ---------------------------------------------------------------------------
// Kernel B: fused gather + pitch embed (PDIM=4) + energy embed (EDIM=1) + bias.
// blockDim = 384: each thread owns a fixed channel-quad c4 = tid % 96, so its
// weights (4 float4 pitch_w rows, 4 energy_w, 4 combined bias) stay in
// registers for the whole row loop. 4 rows processed per block-iteration
// (sub = tid / 96); grid-stride over 4-row groups.
// ---------------------------------------------------------------------------
__global__ __launch_bounds__(384) void fuse_kernel(
    const float*  __restrict__ hs,        // [B, T_IN, ADIM]
    const int*    __restrict__ idx,       // [B, T_OUT]
    const float4* __restrict__ pitch_t,   // [B*T_OUT] (PDIM=4 packed)
    const float*  __restrict__ energy_t,  // [B*T_OUT] (EDIM=1)
    const float4* __restrict__ pitch_w,   // [ADIM] rows of 4
    const float*  __restrict__ pitch_b,   // [ADIM]
    const float*  __restrict__ energy_w,  // [ADIM]
    const float*  __restrict__ energy_b,  // [ADIM]
    float4*       __restrict__ out)       // [B*T_OUT*kC4]
{
    const int tid = threadIdx.x;
    const int c4  = tid % kC4;   // channel quad, fixed per thread
    const int sub = tid / kC4;   // 0..3: row slot within a block iteration
    const int a0  = c4 * 4;

    // Register-resident weights (loaded once; L1-served, fully reused).
    const float4 w0 = pitch_w[a0];
    const float4 w1 = pitch_w[a0 + 1];
    const float4 w2 = pitch_w[a0 + 2];
    const float4 w3 = pitch_w[a0 + 3];
    const float4 ew = make_float4(energy_w[a0], energy_w[a0 + 1],
                                  energy_w[a0 + 2], energy_w[a0 + 3]);
    const float4 bias = make_float4(pitch_b[a0]     + energy_b[a0],
                                    pitch_b[a0 + 1] + energy_b[a0 + 1],
                                    pitch_b[a0 + 2] + energy_b[a0 + 2],
                                    pitch_b[a0 + 3] + energy_b[a0 + 3]);

    const long nrows = (long)kB * kTout;  // 65536
    for (long row = (long)blockIdx.x * 4 + sub; row < nrows;
         row += 4L * gridDim.x) {
        const int src = idx[row];
        float4 h = make_float4(0.f, 0.f, 0.f, 0.f);
        if (src >= 0) {
            const long b = row >> 11;  // row / T_OUT (T_OUT = 2048)
            h = *(const float4*)(hs + (b * kTin + src) * (long)kA + a0);
        }
        const float4 pt = pitch_t[row];
        const float  e  = energy_t[row];
        float4 o;
        o.x = h.x + pt.x * w0.x + pt.y * w0.y + pt.z * w0.z + pt.w * w0.w + e * ew.x + bias.x;
        o.y = h.y + pt.x * w1.x + pt.y * w1.y + pt.z * w1.z + pt.w * w1.w + e * ew.y + bias.y;
        o.z = h.z + pt.x * w2.x + pt.y * w2.y + pt.z * w2.z + pt.w * w2.w + e * ew.z + bias.z;
        o.w = h.w + pt.x * w3.x + pt.y * w3.y + pt.z * w3.z + pt.w * w3.w + e * ew.w + bias.w;
        out[row * kC4 + c4] = o;
    }
}

extern "C" void kernel_launch(void* const* d_in, const int* in_sizes, int n_in,
                              void* d_out, int out_size, void* d_ws, size_t ws_size,
                              hipStream_t stream) {
    // setup_inputs() order:
    // 0 hs[32,512,384] f32 | 1 durations[32,512] int | 2 input_lengths[32] int
    // 3 pitch_target[32,2048,4] f32 | 4 energy_target[32,2048,1] f32
    // 5 duration_mask (unused) | 6 variance_mask (unused)
    // 7 pitch_w[384,4] f32 | 8 pitch_b[384] f32 | 9 energy_w[384,1] f32 | 10 energy_b[384] f32
    const float* hs            = (const float*)d_in[0];
    const int*   durations     = (const int*)d_in[1];
    const int*   input_lengths = (const int*)d_in[2];
    const float* pitch_t       = (const float*)d_in[3];
    const float* energy_t      = (const float*)d_in[4];
    const float* pitch_w       = (const float*)d_in[7];
    const float* pitch_b       = (const float*)d_in[8];
    const float* energy_w      = (const float*)d_in[9];
    const float* energy_b      = (const float*)d_in[10];
    float* out = (float*)d_out;
    int*   idx = (int*)d_ws;   // 32*2048 ints = 256 KB scratch

    lr_index_kernel<<<kB, kTin, 0, stream>>>(durations, input_lengths, idx);
    fuse_kernel<<<1024, 384, 0, stream>>>(hs, idx,
        (const float4*)pitch_t, energy_t,
        (const float4*)pitch_w, pitch_b, energy_w, energy_b,
        (float4*)out);
}